// Round 2
// baseline (219.266 us; speedup 1.0000x reference)
//
#include <hip/hip_runtime.h>

// Problem constants (fixed by setup_inputs in the reference)
#define S_SPK 2
#define B_BATCH 4
#define M_MIC 4
#define W_TAP 3
#define F_FREQ 257
#define T_TIME 512
#define C_CH 4
#define FT (F_FREQ * T_TIME)      // 131584

// Thread mapping: one wave handles one full f-row; lane l -> t0 = 8*l.
// Block = 128 threads = 2 waves = 2 consecutive f-rows.
// Grid = (ceil(F/2)=129, S*B=8).

__global__ void zero_ws_kernel(float* ws) {
    if (threadIdx.x < 16) ws[threadIdx.x] = 0.0f;
}

__global__ __launch_bounds__(128) void pit_main_kernel(
    const float* __restrict__ masks,   // [S,B,M,W,F,T,2]
    const float* __restrict__ mixr,    // [S,B,M,F,T]
    const float* __restrict__ mixi,    // [S,B,M,F,T]
    const float* __restrict__ tgtr,    // [S,B,C,F,T] (use c=0)
    const float* __restrict__ tgti,    // [S,B,C,F,T]
    float* __restrict__ ws)
{
    const int sb   = blockIdx.y;             // so*B + b
    const int so   = sb / B_BATCH;
    const int b    = sb % B_BATCH;
    const int wave = threadIdx.x >> 6;
    const int lane = threadIdx.x & 63;
    const int f    = blockIdx.x * 2 + wave;
    const int t0   = lane * 8;

    float L0 = 0.0f, L1 = 0.0f;

    if (f < F_FREQ) {
        float orr[8], oii[8];
        #pragma unroll
        for (int j = 0; j < 8; ++j) { orr[j] = 0.0f; oii[j] = 0.0f; }

        const int ft       = f * T_TIME + t0;           // lane-varying row offset
        const int mixBase  = sb * M_MIC * FT;           // uniform
        const int mskBase  = sb * M_MIC * W_TAP * FT * 2; // uniform

        #pragma unroll
        for (int m = 0; m < M_MIC; ++m) {
            const float* mrp = mixr + mixBase + m * FT + ft;  // points at t0
            const float* mip = mixi + mixBase + m * FT + ft;

            // window t0-1 .. t0+8 (10 values), vectorized middle, predicated edges
            float rwin[10], iwin[10];
            {
                const float4 ra = *(const float4*)(mrp);
                const float4 rb = *(const float4*)(mrp + 4);
                const float4 ia = *(const float4*)(mip);
                const float4 ib = *(const float4*)(mip + 4);
                rwin[0] = (t0 > 0) ? mrp[-1] : 0.0f;
                iwin[0] = (t0 > 0) ? mip[-1] : 0.0f;
                rwin[1] = ra.x; rwin[2] = ra.y; rwin[3] = ra.z; rwin[4] = ra.w;
                rwin[5] = rb.x; rwin[6] = rb.y; rwin[7] = rb.z; rwin[8] = rb.w;
                iwin[1] = ia.x; iwin[2] = ia.y; iwin[3] = ia.z; iwin[4] = ia.w;
                iwin[5] = ib.x; iwin[6] = ib.y; iwin[7] = ib.z; iwin[8] = ib.w;
                rwin[9] = (t0 + 8 < T_TIME) ? mrp[8] : 0.0f;
                iwin[9] = (t0 + 8 < T_TIME) ? mip[8] : 0.0f;
            }

            #pragma unroll
            for (int w = 0; w < W_TAP; ++w) {
                // masks[(sb),m,w,f,t0..t0+7,re/im] -> 4 aligned float4 (64B)
                const float4* mp = (const float4*)(masks + mskBase + (m * W_TAP + w) * FT * 2 + ft * 2);
                #pragma unroll
                for (int k = 0; k < 4; ++k) {
                    const float4 fl = mp[k];
                    const int j0 = 2 * k, j1 = 2 * k + 1;
                    // out += win * filt (complex); win index j+w (rwin[0] is t0-1)
                    orr[j0] += rwin[j0 + w] * fl.x - iwin[j0 + w] * fl.y;
                    oii[j0] += rwin[j0 + w] * fl.y + iwin[j0 + w] * fl.x;
                    orr[j1] += rwin[j1 + w] * fl.z - iwin[j1 + w] * fl.w;
                    oii[j1] += rwin[j1 + w] * fl.w + iwin[j1 + w] * fl.z;
                }
            }
        }

        // targets, channel 0, both candidate speakers st = 0,1
        #pragma unroll
        for (int st = 0; st < S_SPK; ++st) {
            const int tBase = (st * B_BATCH + b) * C_CH * FT + ft;
            const float4 tra = *(const float4*)(tgtr + tBase);
            const float4 trb = *(const float4*)(tgtr + tBase + 4);
            const float4 tia = *(const float4*)(tgti + tBase);
            const float4 tib = *(const float4*)(tgti + tBase + 4);
            const float tr[8] = {tra.x, tra.y, tra.z, tra.w, trb.x, trb.y, trb.z, trb.w};
            const float ti[8] = {tia.x, tia.y, tia.z, tia.w, tib.x, tib.y, tib.z, tib.w};
            float acc = 0.0f;
            #pragma unroll
            for (int j = 0; j < 8; ++j) {
                const float ao = sqrtf(orr[j] * orr[j] + oii[j] * oii[j]);
                const float at = sqrtf(tr[j] * tr[j] + ti[j] * ti[j]);
                acc += fabsf(tr[j] - orr[j]) + fabsf(ti[j] - oii[j]) + fabsf(at - ao);
            }
            if (st == 0) L0 = acc; else L1 = acc;
        }
    }

    // wave(64) shuffle reduction
    #pragma unroll
    for (int off = 32; off > 0; off >>= 1) {
        L0 += __shfl_down(L0, off, 64);
        L1 += __shfl_down(L1, off, 64);
    }
    __shared__ float s0[2], s1[2];
    if (lane == 0) { s0[wave] = L0; s1[wave] = L1; }
    __syncthreads();
    if (threadIdx.x == 0) {
        atomicAdd(&ws[(so * S_SPK + 0) * B_BATCH + b], s0[0] + s0[1]);
        atomicAdd(&ws[(so * S_SPK + 1) * B_BATCH + b], s1[0] + s1[1]);
    }
}

__global__ void pit_final_kernel(const float* __restrict__ ws,
                                 float* __restrict__ out, int num_utts) {
    if (threadIdx.x == 0 && blockIdx.x == 0) {
        float acc = 0.0f;
        for (int b = 0; b < B_BATCH; ++b) {
            // perm (0,1): L[0][0] + L[1][1];  perm (1,0): L[0][1] + L[1][0]
            const float pid = ws[(0 * S_SPK + 0) * B_BATCH + b] + ws[(1 * S_SPK + 1) * B_BATCH + b];
            const float psw = ws[(0 * S_SPK + 1) * B_BATCH + b] + ws[(1 * S_SPK + 0) * B_BATCH + b];
            const float sc0 = 3.0f * pid / (float)S_SPK;
            const float sc1 = 3.0f * psw / (float)S_SPK;
            acc += fminf(sc0, sc1);
        }
        out[0] = acc / (float)num_utts;
    }
}

extern "C" void kernel_launch(void* const* d_in, const int* in_sizes, int n_in,
                              void* d_out, int out_size, void* d_ws, size_t ws_size,
                              hipStream_t stream) {
    const float* masks = (const float*)d_in[0];
    const float* mixr  = (const float*)d_in[1];
    const float* mixi  = (const float*)d_in[2];
    const float* tgtr  = (const float*)d_in[3];
    const float* tgti  = (const float*)d_in[4];
    // input_sizes values are never used by the reference; only its length is.
    const int num_utts = in_sizes[5];

    float* ws  = (float*)d_ws;
    float* out = (float*)d_out;

    zero_ws_kernel<<<1, 64, 0, stream>>>(ws);

    dim3 grid((F_FREQ + 1) / 2, S_SPK * B_BATCH);   // (129, 8)
    pit_main_kernel<<<grid, 128, 0, stream>>>(masks, mixr, mixi, tgtr, tgti, ws);

    pit_final_kernel<<<1, 64, 0, stream>>>(ws, out, num_utts);
}

// Round 3
// 213.683 us; speedup vs baseline: 1.0261x; 1.0261x over previous
//
#include <hip/hip_runtime.h>

// Problem constants (fixed by setup_inputs in the reference)
#define S_SPK 2
#define B_BATCH 4
#define M_MIC 4
#define W_TAP 3
#define F_FREQ 257
#define T_TIME 512
#define C_CH 4
#define FT (F_FREQ * T_TIME)      // 131584
#define MW (M_MIC * W_TAP)        // 12 mask rows per (sb,f)
#define ROW (T_TIME * 2)          // 1024 floats per row (re/im interleaved)

// Async global->LDS, 16B per lane, 64 lanes = 1KB per instruction.
// LDS dest semantics: wave-uniform base + lane*16 — we compute each lane's
// lds ptr as base + lane*16 so the layout matches exactly.
__device__ __forceinline__ void async_copy16(const float* g, float* l) {
    __builtin_amdgcn_global_load_lds(
        (const __attribute__((address_space(1))) void*)g,
        (__attribute__((address_space(3))) void*)l,
        16, 0, 0);
}

__global__ void zero_ws_kernel(float* ws) {
    if (threadIdx.x < 16) ws[threadIdx.x] = 0.0f;
}

// Block = 256 threads (4 waves) handles one (sb, f): all M*W mask rows staged
// to LDS via async DMA (48KB, 48 instructions, zero VGPR cost); mixture
// windows + targets via direct loads issued before the barrier.
// Grid = (257, 8). LDS 48KB -> 3 blocks/CU.
__global__ __launch_bounds__(256) void pit_main_kernel(
    const float* __restrict__ masks,   // [S,B,M,W,F,T,2]
    const float* __restrict__ mixr,    // [S,B,M,F,T]
    const float* __restrict__ mixi,    // [S,B,M,F,T]
    const float* __restrict__ tgtr,    // [S,B,C,F,T] (use c=0)
    const float* __restrict__ tgti,    // [S,B,C,F,T]
    float* __restrict__ ws)
{
    __shared__ float maskLDS[MW * ROW];          // 48 KB
    __shared__ float s0[4], s1[4];

    const int sb   = blockIdx.y;                 // so*B + b
    const int so   = sb / B_BATCH;
    const int b    = sb % B_BATCH;
    const int f    = blockIdx.x;
    const int tid  = threadIdx.x;
    const int wave = tid >> 6;
    const int lane = tid & 63;

    // ---- stage masks: 48 x 1KB DMA instructions, 12 per wave ----
    {
        // global index of masks[sb, m=0, w=0, f, t=0, 0]
        const long mskBase = (long)sb * MW * (FT * 2L) + (long)f * ROW;
        #pragma unroll
        for (int j = 0; j < 12; ++j) {
            const int inst = wave * 12 + j;      // 0..47 (wave-uniform)
            const int row  = inst >> 2;          // (m*W + w), 0..11
            const int seg  = inst & 3;           // quarter of the 1024-float row
            const float* g = masks + mskBase + (long)row * (FT * 2L) + seg * 256 + lane * 4;
            float*       l = maskLDS + row * ROW + seg * 256 + lane * 4;
            async_copy16(g, l);
        }
    }

    // ---- direct loads (issued before the barrier; drain overlaps DMA) ----
    const int t0 = tid * 2;                      // this thread: t0, t0+1
    float mr[M_MIC][4], mi[M_MIC][4];            // window t0-1 .. t0+2
    {
        const long mixBase = (long)sb * M_MIC * (long)FT + (long)f * T_TIME + t0;
        #pragma unroll
        for (int m = 0; m < M_MIC; ++m) {
            const float* mrp = mixr + mixBase + (long)m * FT;
            const float* mip = mixi + mixBase + (long)m * FT;
            const int km = (t0 > 0) ? -1 : 0;            // clamped, masked after
            const int kp = (t0 + 2 < T_TIME) ? 2 : 1;
            float r0 = mrp[km], i0 = mip[km];
            float r3 = mrp[kp], i3 = mip[kp];
            mr[m][0] = (t0 > 0) ? r0 : 0.0f;
            mi[m][0] = (t0 > 0) ? i0 : 0.0f;
            mr[m][1] = mrp[0];  mi[m][1] = mip[0];
            mr[m][2] = mrp[1];  mi[m][2] = mip[1];
            mr[m][3] = (t0 + 2 < T_TIME) ? r3 : 0.0f;
            mi[m][3] = (t0 + 2 < T_TIME) ? i3 : 0.0f;
        }
    }
    float2 tr[2], ti[2];
    {
        #pragma unroll
        for (int st = 0; st < S_SPK; ++st) {
            const long tB = ((long)(st * B_BATCH + b) * C_CH) * FT + (long)f * T_TIME + t0;
            tr[st] = *(const float2*)(tgtr + tB);
            ti[st] = *(const float2*)(tgti + tB);
        }
    }

    __syncthreads();   // drains DMA (vmcnt(0)) + makes maskLDS visible

    // ---- compute: complex MAC over (m,w) from LDS masks + register windows ----
    float or0 = 0.f, oi0 = 0.f, or1 = 0.f, oi1 = 0.f;
    #pragma unroll
    for (int m = 0; m < M_MIC; ++m) {
        #pragma unroll
        for (int w = 0; w < W_TAP; ++w) {
            // {re(t0), im(t0), re(t0+1), im(t0+1)} — conflict-free ds_read_b128
            const float4 fl = *(const float4*)(maskLDS + (m * W_TAP + w) * ROW + t0 * 2);
            const float wr0 = mr[m][w],     wi0 = mi[m][w];
            const float wr1 = mr[m][w + 1], wi1 = mi[m][w + 1];
            or0 += wr0 * fl.x - wi0 * fl.y;
            oi0 += wr0 * fl.y + wi0 * fl.x;
            or1 += wr1 * fl.z - wi1 * fl.w;
            oi1 += wr1 * fl.w + wi1 * fl.z;
        }
    }

    float L0, L1;
    {
        const float ao0 = sqrtf(or0 * or0 + oi0 * oi0);
        const float ao1 = sqrtf(or1 * or1 + oi1 * oi1);
        const float at00 = sqrtf(tr[0].x * tr[0].x + ti[0].x * ti[0].x);
        const float at01 = sqrtf(tr[0].y * tr[0].y + ti[0].y * ti[0].y);
        const float at10 = sqrtf(tr[1].x * tr[1].x + ti[1].x * ti[1].x);
        const float at11 = sqrtf(tr[1].y * tr[1].y + ti[1].y * ti[1].y);
        L0 = fabsf(tr[0].x - or0) + fabsf(ti[0].x - oi0) + fabsf(at00 - ao0)
           + fabsf(tr[0].y - or1) + fabsf(ti[0].y - oi1) + fabsf(at01 - ao1);
        L1 = fabsf(tr[1].x - or0) + fabsf(ti[1].x - oi0) + fabsf(at10 - ao0)
           + fabsf(tr[1].y - or1) + fabsf(ti[1].y - oi1) + fabsf(at11 - ao1);
    }

    // ---- reduction: wave shuffle -> LDS -> one atomic per block ----
    #pragma unroll
    for (int off = 32; off > 0; off >>= 1) {
        L0 += __shfl_down(L0, off, 64);
        L1 += __shfl_down(L1, off, 64);
    }
    if (lane == 0) { s0[wave] = L0; s1[wave] = L1; }
    __syncthreads();
    if (tid == 0) {
        atomicAdd(&ws[(so * S_SPK + 0) * B_BATCH + b], s0[0] + s0[1] + s0[2] + s0[3]);
        atomicAdd(&ws[(so * S_SPK + 1) * B_BATCH + b], s1[0] + s1[1] + s1[2] + s1[3]);
    }
}

__global__ void pit_final_kernel(const float* __restrict__ ws,
                                 float* __restrict__ out, int num_utts) {
    if (threadIdx.x == 0 && blockIdx.x == 0) {
        float acc = 0.0f;
        for (int b = 0; b < B_BATCH; ++b) {
            // perm (0,1): L[0][0] + L[1][1];  perm (1,0): L[0][1] + L[1][0]
            const float pid = ws[(0 * S_SPK + 0) * B_BATCH + b] + ws[(1 * S_SPK + 1) * B_BATCH + b];
            const float psw = ws[(0 * S_SPK + 1) * B_BATCH + b] + ws[(1 * S_SPK + 0) * B_BATCH + b];
            const float sc0 = 3.0f * pid / (float)S_SPK;
            const float sc1 = 3.0f * psw / (float)S_SPK;
            acc += fminf(sc0, sc1);
        }
        out[0] = acc / (float)num_utts;
    }
}

extern "C" void kernel_launch(void* const* d_in, const int* in_sizes, int n_in,
                              void* d_out, int out_size, void* d_ws, size_t ws_size,
                              hipStream_t stream) {
    const float* masks = (const float*)d_in[0];
    const float* mixr  = (const float*)d_in[1];
    const float* mixi  = (const float*)d_in[2];
    const float* tgtr  = (const float*)d_in[3];
    const float* tgti  = (const float*)d_in[4];
    // input_sizes values are never used by the reference; only its length is.
    const int num_utts = in_sizes[5];

    float* ws  = (float*)d_ws;
    float* out = (float*)d_out;

    zero_ws_kernel<<<1, 64, 0, stream>>>(ws);

    dim3 grid(F_FREQ, S_SPK * B_BATCH);     // (257, 8)
    pit_main_kernel<<<grid, 256, 0, stream>>>(masks, mixr, mixi, tgtr, tgti, ws);

    pit_final_kernel<<<1, 64, 0, stream>>>(ws, out, num_utts);
}